// Round 1
// baseline (642.976 us; speedup 1.0000x reference)
//
#include <hip/hip_runtime.h>

// PhotometricLoss: total = 0.8*L1 + 0.2*DSSIM, fused single-pass SSIM via
// separable 11x11 Gaussian (sigma=1.5), SAME zero padding.
// Layout: inputs BHWC fp32 (B=4,H=1080,W=1920,C=3). One block = one (b,c) 32x32 tile.

#define TW 32
#define TH 32
#define HALO 5
#define KS 11
#define IW (TW + 2*HALO)      // 42
#define IH (TH + 2*HALO)      // 42
#define IWP 43                // padded row stride for sx/sy (bank spread)
#define HCP 33                // padded col count for hconv (breaks 160%32==0)

__global__ __launch_bounds__(256) void photo_main(
    const float* __restrict__ xin, const float* __restrict__ yin,
    double* __restrict__ accum, int B, int H, int W, int C)
{
    __shared__ float sx[IH][IWP];
    __shared__ float sy[IH][IWP];
    __shared__ float hc[IH][HCP][5];   // h-convolved {x, y, x2, y2, xy}
    __shared__ float red[8];

    // Gaussian weights, computed as the reference does (fp32 exp, normalize)
    float g[KS];
    {
        float s = 0.f;
        #pragma unroll
        for (int i = 0; i < KS; ++i) {
            float d = (float)(i - 5);
            g[i] = expf(-d * d / 4.5f);
            s += g[i];
        }
        float inv = 1.0f / s;
        #pragma unroll
        for (int i = 0; i < KS; ++i) g[i] *= inv;
    }

    const int tid  = threadIdx.x;
    const int bz   = blockIdx.z;          // b*C + c
    const int b    = bz / C, c = bz % C;
    const int row0 = blockIdx.y * TH;
    const int col0 = blockIdx.x * TW;

    const float* __restrict__ xb = xin + (long)b * H * W * C + c;
    const float* __restrict__ yb = yin + (long)b * H * W * C + c;

    // ---- Phase 1a: stage 42x42 halo tile of x and y (0 outside image = SAME pad)
    for (int i = tid; i < IH * IW; i += 256) {
        int r  = i / IW, cc = i - r * IW;
        int gr = row0 - HALO + r;
        int gc = col0 - HALO + cc;
        float vx = 0.f, vy = 0.f;
        if ((unsigned)gr < (unsigned)H && (unsigned)gc < (unsigned)W) {
            long off = ((long)gr * W + gc) * C;
            vx = xb[off];
            vy = yb[off];
        }
        sx[r][cc] = vx;
        sy[r][cc] = vy;
    }
    __syncthreads();

    // ---- Phase 1b: horizontal 11-tap conv of {x,y,x2,y2,xy}; 4 output cols/thread
    // 42 rows * 8 col-groups = 336 work items
    for (int t = tid; t < IH * (TW / 4); t += 256) {
        int r  = t >> 3;
        int cb = (t & 7) * 4;
        float a[4][5];
        #pragma unroll
        for (int u = 0; u < 4; ++u)
            #pragma unroll
            for (int q = 0; q < 5; ++q) a[u][q] = 0.f;
        #pragma unroll
        for (int k = 0; k < 15; ++k) {          // taps cb..cb+14 cover 4 outputs
            float vx = sx[r][cb + k];
            float vy = sy[r][cb + k];
            float xx = vx * vx, yy = vy * vy, xy = vx * vy;
            #pragma unroll
            for (int u = 0; u < 4; ++u) {
                int m = k - u;                   // compile-time after unroll
                if (m >= 0 && m < KS) {
                    float w = g[m];
                    a[u][0] += w * vx;
                    a[u][1] += w * vy;
                    a[u][2] += w * xx;
                    a[u][3] += w * yy;
                    a[u][4] += w * xy;
                }
            }
        }
        #pragma unroll
        for (int u = 0; u < 4; ++u) {
            #pragma unroll
            for (int q = 0; q < 5; ++q) hc[r][cb + u][q] = a[u][q];
        }
    }
    __syncthreads();

    // ---- Phase 2: vertical 11-tap conv + SSIM + L1. 256 threads = 32 cols x 8
    // row-groups, 4 rows each -> full 32x32 tile in one shot.
    const float C1c = 1e-4f, C2c = 9e-4f;
    float ssim_sum = 0.f, l1_sum = 0.f;
    {
        int cc = tid & 31;
        int rb = (tid >> 5) * 4;
        float acc[4][5];
        #pragma unroll
        for (int u = 0; u < 4; ++u)
            #pragma unroll
            for (int q = 0; q < 5; ++q) acc[u][q] = 0.f;
        #pragma unroll
        for (int k = 0; k < 14; ++k) {          // taps rb..rb+13 cover 4 output rows
            float v0 = hc[rb + k][cc][0];
            float v1 = hc[rb + k][cc][1];
            float v2 = hc[rb + k][cc][2];
            float v3 = hc[rb + k][cc][3];
            float v4 = hc[rb + k][cc][4];
            #pragma unroll
            for (int u = 0; u < 4; ++u) {
                int m = k - u;
                if (m >= 0 && m < KS) {
                    float w = g[m];
                    acc[u][0] += w * v0;
                    acc[u][1] += w * v1;
                    acc[u][2] += w * v2;
                    acc[u][3] += w * v3;
                    acc[u][4] += w * v4;
                }
            }
        }
        #pragma unroll
        for (int u = 0; u < 4; ++u) {
            int gr = row0 + rb + u;
            int gc = col0 + cc;
            if (gr < H && gc < W) {
                float mu1 = acc[u][0], mu2 = acc[u][1];
                float mu1s = mu1 * mu1, mu2s = mu2 * mu2, mu12 = mu1 * mu2;
                float s1  = acc[u][2] - mu1s;
                float s2  = acc[u][3] - mu2s;
                float s12 = acc[u][4] - mu12;
                float num = (2.f * mu12 + C1c) * (2.f * s12 + C2c);
                float den = (mu1s + mu2s + C1c) * (s1 + s2 + C2c);
                ssim_sum += num / den;
                float vx = sx[rb + u + HALO][cc + HALO];
                float vy = sy[rb + u + HALO][cc + HALO];
                l1_sum += fabsf(vx - vy);
            }
        }
    }

    // ---- Block reduction (wave64 shuffle + LDS), then one double atomic each
    #pragma unroll
    for (int off = 32; off > 0; off >>= 1) {
        ssim_sum += __shfl_down(ssim_sum, off);
        l1_sum   += __shfl_down(l1_sum, off);
    }
    int wave = tid >> 6;
    if ((tid & 63) == 0) { red[wave] = ssim_sum; red[4 + wave] = l1_sum; }
    __syncthreads();
    if (tid == 0) {
        float s = red[0] + red[1] + red[2] + red[3];
        float l = red[4] + red[5] + red[6] + red[7];
        atomicAdd(&accum[0], (double)l);
        atomicAdd(&accum[1], (double)s);
    }
}

__global__ void photo_final(const double* __restrict__ accum,
                            float* __restrict__ out, double invN)
{
    double l1    = accum[0] * invN;
    double ssim  = accum[1] * invN;
    double dssim = (1.0 - ssim) * 0.5;
    out[0] = (float)(0.8 * l1 + 0.2 * dssim);
    out[1] = (float)l1;
    out[2] = (float)dssim;
}

extern "C" void kernel_launch(void* const* d_in, const int* in_sizes, int n_in,
                              void* d_out, int out_size, void* d_ws, size_t ws_size,
                              hipStream_t stream)
{
    const int H = 1080, W = 1920, C = 3;
    const float* x = (const float*)d_in[0];
    const float* y = (const float*)d_in[1];
    int B = in_sizes[0] / (H * W * C);

    double* accum = (double*)d_ws;
    hipMemsetAsync(d_ws, 0, 2 * sizeof(double), stream);

    dim3 grid((W + TW - 1) / TW, (H + TH - 1) / TH, B * C);
    photo_main<<<grid, dim3(256), 0, stream>>>(x, y, accum, B, H, W, C);

    double invN = 1.0 / ((double)B * H * W * C);
    photo_final<<<1, 1, 0, stream>>>(accum, (float*)d_out, invN);
}

// Round 2
// 203.603 us; speedup vs baseline: 3.1580x; 3.1580x over previous
//
#include <hip/hip_runtime.h>
#include <hip/hip_fp16.h>

// PhotometricLoss: total = 0.8*L1 + 0.2*DSSIM, fused single-pass SSIM via
// separable 11x11 Gaussian (sigma=1.5), SAME zero padding.
// Inputs BHWC fp32 (B=4,H=1080,W=1920,C=3). One block = one (b,c) 32x32 tile.
// R2: hc moments stored as fp16 planes -> LDS 42.5KB->29.6KB -> 5 blocks/CU;
//     atomics hashed over 512 slots to kill same-address contention.

#define TW 32
#define TH 32
#define HALO 5
#define KS 11
#define IW (TW + 2*HALO)      // 42
#define IH (TH + 2*HALO)      // 42
#define IWP 43                // padded row stride for sx/sy (bank spread)
#define HCW 36                // hc row stride in halves: 72 B, 8B-aligned rows
#define NSLOT 512

__global__ __launch_bounds__(256) void photo_main(
    const float* __restrict__ xin, const float* __restrict__ yin,
    double* __restrict__ accum, int B, int H, int W, int C)
{
    __shared__ float sx[IH][IWP];
    __shared__ float sy[IH][IWP];
    __shared__ __half hc[5][IH][HCW];   // h-convolved {x, y, x2, y2, xy} planes
    __shared__ float red[8];

    // Gaussian weights, computed as the reference does (fp32 exp, normalize)
    float g[KS];
    {
        float s = 0.f;
        #pragma unroll
        for (int i = 0; i < KS; ++i) {
            float d = (float)(i - 5);
            g[i] = expf(-d * d / 4.5f);
            s += g[i];
        }
        float inv = 1.0f / s;
        #pragma unroll
        for (int i = 0; i < KS; ++i) g[i] *= inv;
    }

    const int tid  = threadIdx.x;
    const int bz   = blockIdx.z;          // b*C + c
    const int b    = bz / C, c = bz % C;
    const int row0 = blockIdx.y * TH;
    const int col0 = blockIdx.x * TW;

    const float* __restrict__ xb = xin + (long)b * H * W * C + c;
    const float* __restrict__ yb = yin + (long)b * H * W * C + c;

    // ---- Phase 1a: stage 42x42 halo tile of x and y (0 outside image = SAME pad)
    for (int i = tid; i < IH * IW; i += 256) {
        int r  = i / IW, cc = i - r * IW;
        int gr = row0 - HALO + r;
        int gc = col0 - HALO + cc;
        float vx = 0.f, vy = 0.f;
        if ((unsigned)gr < (unsigned)H && (unsigned)gc < (unsigned)W) {
            long off = ((long)gr * W + gc) * C;
            vx = xb[off];
            vy = yb[off];
        }
        sx[r][cc] = vx;
        sy[r][cc] = vy;
    }
    __syncthreads();

    // ---- Phase 1b: horizontal 11-tap conv of {x,y,x2,y2,xy}; 4 output cols/thread
    // 42 rows * 8 col-groups = 336 work items
    for (int t = tid; t < IH * (TW / 4); t += 256) {
        int r  = t >> 3;
        int cb = (t & 7) * 4;
        float a[4][5];
        #pragma unroll
        for (int u = 0; u < 4; ++u)
            #pragma unroll
            for (int q = 0; q < 5; ++q) a[u][q] = 0.f;
        #pragma unroll
        for (int k = 0; k < 15; ++k) {          // taps cb..cb+14 cover 4 outputs
            float vx = sx[r][cb + k];
            float vy = sy[r][cb + k];
            float xx = vx * vx, yy = vy * vy, xy = vx * vy;
            #pragma unroll
            for (int u = 0; u < 4; ++u) {
                int m = k - u;                   // compile-time after unroll
                if (m >= 0 && m < KS) {
                    float w = g[m];
                    a[u][0] += w * vx;
                    a[u][1] += w * vy;
                    a[u][2] += w * xx;
                    a[u][3] += w * yy;
                    a[u][4] += w * xy;
                }
            }
        }
        #pragma unroll
        for (int q = 0; q < 5; ++q) {
            __half2* p = (__half2*)&hc[q][r][cb];
            p[0] = __halves2half2(__float2half(a[0][q]), __float2half(a[1][q]));
            p[1] = __halves2half2(__float2half(a[2][q]), __float2half(a[3][q]));
        }
    }
    __syncthreads();

    // ---- Phase 2: vertical 11-tap conv + SSIM + L1. 256 threads = 32 cols x 8
    // row-groups, 4 rows each -> full 32x32 tile in one shot.
    const float C1c = 1e-4f, C2c = 9e-4f;
    float ssim_sum = 0.f, l1_sum = 0.f;
    {
        int cc = tid & 31;
        int rb = (tid >> 5) * 4;
        float acc[4][5];
        #pragma unroll
        for (int u = 0; u < 4; ++u)
            #pragma unroll
            for (int q = 0; q < 5; ++q) acc[u][q] = 0.f;
        #pragma unroll
        for (int k = 0; k < 14; ++k) {          // taps rb..rb+13 cover 4 output rows
            int rr = rb + k;
            float v0 = __half2float(hc[0][rr][cc]);
            float v1 = __half2float(hc[1][rr][cc]);
            float v2 = __half2float(hc[2][rr][cc]);
            float v3 = __half2float(hc[3][rr][cc]);
            float v4 = __half2float(hc[4][rr][cc]);
            #pragma unroll
            for (int u = 0; u < 4; ++u) {
                int m = k - u;
                if (m >= 0 && m < KS) {
                    float w = g[m];
                    acc[u][0] += w * v0;
                    acc[u][1] += w * v1;
                    acc[u][2] += w * v2;
                    acc[u][3] += w * v3;
                    acc[u][4] += w * v4;
                }
            }
        }
        #pragma unroll
        for (int u = 0; u < 4; ++u) {
            int gr = row0 + rb + u;
            int gc = col0 + cc;
            if (gr < H && gc < W) {
                float mu1 = acc[u][0], mu2 = acc[u][1];
                float mu1s = mu1 * mu1, mu2s = mu2 * mu2, mu12 = mu1 * mu2;
                float s1  = acc[u][2] - mu1s;
                float s2  = acc[u][3] - mu2s;
                float s12 = acc[u][4] - mu12;
                float num = (2.f * mu12 + C1c) * (2.f * s12 + C2c);
                float den = (mu1s + mu2s + C1c) * (s1 + s2 + C2c);
                ssim_sum += num / den;
                float vx = sx[rb + u + HALO][cc + HALO];
                float vy = sy[rb + u + HALO][cc + HALO];
                l1_sum += fabsf(vx - vy);
            }
        }
    }

    // ---- Block reduction (wave64 shuffle + LDS), then hashed double atomics
    #pragma unroll
    for (int off = 32; off > 0; off >>= 1) {
        ssim_sum += __shfl_down(ssim_sum, off);
        l1_sum   += __shfl_down(l1_sum, off);
    }
    int wave = tid >> 6;
    if ((tid & 63) == 0) { red[wave] = ssim_sum; red[4 + wave] = l1_sum; }
    __syncthreads();
    if (tid == 0) {
        float s = red[0] + red[1] + red[2] + red[3];
        float l = red[4] + red[5] + red[6] + red[7];
        int bid = blockIdx.x + gridDim.x * (blockIdx.y + gridDim.y * blockIdx.z);
        double* slot = accum + (size_t)(bid & (NSLOT - 1)) * 2;
        atomicAdd(&slot[0], (double)l);
        atomicAdd(&slot[1], (double)s);
    }
}

__global__ __launch_bounds__(NSLOT) void photo_final(
    const double* __restrict__ accum, float* __restrict__ out, double invN)
{
    __shared__ double sl[8], ss[8];
    int tid = threadIdx.x;
    double l = accum[tid * 2 + 0];
    double s = accum[tid * 2 + 1];
    #pragma unroll
    for (int off = 32; off > 0; off >>= 1) {
        l += __shfl_down(l, off);
        s += __shfl_down(s, off);
    }
    if ((tid & 63) == 0) { sl[tid >> 6] = l; ss[tid >> 6] = s; }
    __syncthreads();
    if (tid == 0) {
        double L = 0.0, S = 0.0;
        #pragma unroll
        for (int i = 0; i < NSLOT / 64; ++i) { L += sl[i]; S += ss[i]; }
        double l1    = L * invN;
        double ssim  = S * invN;
        double dssim = (1.0 - ssim) * 0.5;
        out[0] = (float)(0.8 * l1 + 0.2 * dssim);
        out[1] = (float)l1;
        out[2] = (float)dssim;
    }
}

extern "C" void kernel_launch(void* const* d_in, const int* in_sizes, int n_in,
                              void* d_out, int out_size, void* d_ws, size_t ws_size,
                              hipStream_t stream)
{
    const int H = 1080, W = 1920, C = 3;
    const float* x = (const float*)d_in[0];
    const float* y = (const float*)d_in[1];
    int B = in_sizes[0] / (H * W * C);

    double* accum = (double*)d_ws;
    hipMemsetAsync(d_ws, 0, NSLOT * 2 * sizeof(double), stream);

    dim3 grid((W + TW - 1) / TW, (H + TH - 1) / TH, B * C);
    photo_main<<<grid, dim3(256), 0, stream>>>(x, y, accum, B, H, W, C);

    double invN = 1.0 / ((double)B * H * W * C);
    photo_final<<<1, NSLOT, 0, stream>>>(accum, (float*)d_out, invN);
}

// Round 3
// 168.715 us; speedup vs baseline: 3.8110x; 1.2068x over previous
//
#include <hip/hip_runtime.h>
#include <hip/hip_fp16.h>

// PhotometricLoss: total = 0.8*L1 + 0.2*DSSIM; fused separable 11x11 Gaussian
// SSIM, SAME zero padding. Inputs BHWC fp32 (B=4,H=1080,W=1920,C=3).
// R3: fp16 staging (packed x,y) + transposed fp16 moment planes (vector LDS
// reads), v_dot2_f32_f16 vertical conv, L1 folded into staging, channel in
// grid.x + bijective XCD swizzle for L2 reuse. LDS 21.5KB -> 7 blocks/CU.

typedef _Float16 h2_t __attribute__((ext_vector_type(2)));

#define TW 32
#define TH 32
#define HALO 5
#define KS 11
#define IW 42
#define IH 42
#define SXW 44      // sxy row stride in uints (176B rows, 16B-aligned)
#define HTR 44      // hcT row stride in halves (88B rows, 8B-aligned)
#define NSLOT 512

__device__ __forceinline__ unsigned short f2hbits(float x) {
    return __half_as_ushort(__float2half(x));
}
__device__ __forceinline__ float h2f_lo(unsigned int v) {
    return __half2float(__ushort_as_half((unsigned short)(v & 0xffffu)));
}
__device__ __forceinline__ float h2f_hi(unsigned int v) {
    return __half2float(__ushort_as_half((unsigned short)(v >> 16)));
}
__device__ __forceinline__ float rfl_f(float x) {
    return __uint_as_float(__builtin_amdgcn_readfirstlane(__float_as_uint(x)));
}
__device__ __forceinline__ unsigned int rfl_u(unsigned int x) {
    return __builtin_amdgcn_readfirstlane(x);
}
__device__ __forceinline__ float dot2h(unsigned int a, unsigned int b, float c) {
#if __has_builtin(__builtin_amdgcn_fdot2)
    return __builtin_amdgcn_fdot2(__builtin_bit_cast(h2_t, a),
                                  __builtin_bit_cast(h2_t, b), c, false);
#else
    h2_t ah = __builtin_bit_cast(h2_t, a), bh = __builtin_bit_cast(h2_t, b);
    return c + (float)ah[0] * (float)bh[0] + (float)ah[1] * (float)bh[1];
#endif
}

__global__ __launch_bounds__(256, 7) void photo_main(
    const float* __restrict__ xin, const float* __restrict__ yin,
    double* __restrict__ accum, int B, int H, int W, int C, int nwg)
{
    __shared__ unsigned int   sxy[IH][SXW];        // packed (x_lo, y_hi) halves
    __shared__ unsigned short hcT[5][TW][HTR];     // transposed moment planes
    __shared__ float red[8];

    // Gaussian weights (as reference: fp32 exp, normalize)
    float g[KS];
    {
        float s = 0.f;
        #pragma unroll
        for (int i = 0; i < KS; ++i) {
            float d = (float)(i - 5);
            g[i] = expf(-d * d / 4.5f);
            s += g[i];
        }
        float inv = 1.0f / s;
        #pragma unroll
        for (int i = 0; i < KS; ++i) g[i] *= inv;
    }
    // fp32 weights in SGPRs for the h-pass
    float gs[KS];
    #pragma unroll
    for (int i = 0; i < KS; ++i) gs[i] = rfl_f(g[i]);
    // packed half2 weight table in SGPRs for the v-pass dot2:
    // pair p covers tap rows rb+2p (lo), rb+2p+1 (hi); m = 2p+e - u
    unsigned int gw[4][7];
    #pragma unroll
    for (int u = 0; u < 4; ++u)
        #pragma unroll
        for (int p = 0; p < 7; ++p) {
            int m0 = 2 * p - u, m1 = 2 * p + 1 - u;
            float w0 = (m0 >= 0 && m0 < KS) ? g[m0] : 0.f;
            float w1 = (m1 >= 0 && m1 < KS) ? g[m1] : 0.f;
            gw[u][p] = rfl_u((unsigned int)f2hbits(w0) |
                             ((unsigned int)f2hbits(w1) << 16));
        }

    // ---- bijective XCD swizzle (nwg % 8 == 0 here), channel fastest in x
    int orig = blockIdx.x + gridDim.x * (blockIdx.y + gridDim.y * blockIdx.z);
    int nid = orig;
    if ((nwg & 7) == 0) nid = (orig & 7) * (nwg >> 3) + (orig >> 3);
    int gx = gridDim.x;
    int bx = nid % gx;
    int rest = nid / gx;
    int by = rest % gridDim.y;
    int b  = rest / gridDim.y;
    int c  = bx % C;
    int tx = bx / C;
    const int row0 = by * TH;
    const int col0 = tx * TW;

    const int tid = threadIdx.x;
    const int imgbase = b * H * W * C + c;

    // ---- Phase 1a: stage 42x42 halo tile as packed halves; fold L1 over the
    // central 32x32 (each image pixel belongs to exactly one tile's center).
    float l1_sum = 0.f;
    #pragma unroll 1
    for (int i = tid; i < IH * IW; i += 256) {
        int r  = i / IW, cc = i - r * IW;
        int gr = row0 - HALO + r;
        int gc = col0 - HALO + cc;
        float vx = 0.f, vy = 0.f;
        bool inb = ((unsigned)gr < (unsigned)H) && ((unsigned)gc < (unsigned)W);
        if (inb) {
            int off = imgbase + (gr * W + gc) * C;
            vx = xin[off];
            vy = yin[off];
        }
        sxy[r][cc] = (unsigned int)f2hbits(vx) | ((unsigned int)f2hbits(vy) << 16);
        if (inb && r >= HALO && r < HALO + TH && cc >= HALO && cc < HALO + TW)
            l1_sum += fabsf(vx - vy);
    }
    __syncthreads();

    // ---- Phase 1b: horizontal 11-tap conv of {x,y,x2,y2,xy}; 4 cols/thread,
    // vectorized b128 reads of the packed tile. Writes transposed planes.
    #pragma unroll 1
    for (int t = tid; t < IH * 8; t += 256) {
        int r  = t >> 3;
        int cb = (t & 7) << 2;
        const uint4* rp = (const uint4*)&sxy[r][cb];
        uint4 q0 = rp[0], q1 = rp[1], q2 = rp[2], q3 = rp[3];
        unsigned int cols[16] = {q0.x, q0.y, q0.z, q0.w, q1.x, q1.y, q1.z, q1.w,
                                 q2.x, q2.y, q2.z, q2.w, q3.x, q3.y, q3.z, q3.w};
        float a[4][5];
        #pragma unroll
        for (int u = 0; u < 4; ++u)
            #pragma unroll
            for (int q = 0; q < 5; ++q) a[u][q] = 0.f;
        #pragma unroll
        for (int k = 0; k < 14; ++k) {
            float vx = h2f_lo(cols[k]);
            float vy = h2f_hi(cols[k]);
            float xx = vx * vx, yy = vy * vy, xy = vx * vy;
            #pragma unroll
            for (int u = 0; u < 4; ++u) {
                int m = k - u;
                if (m >= 0 && m < KS) {
                    float w = gs[m];
                    a[u][0] += w * vx;
                    a[u][1] += w * vy;
                    a[u][2] += w * xx;
                    a[u][3] += w * yy;
                    a[u][4] += w * xy;
                }
            }
        }
        #pragma unroll
        for (int q = 0; q < 5; ++q)
            #pragma unroll
            for (int u = 0; u < 4; ++u)
                hcT[q][cb + u][r] = f2hbits(a[u][q]);
    }
    __syncthreads();

    // ---- Phase 2: vertical conv via fdot2 on contiguous half pairs + SSIM.
    const float C1c = 1e-4f, C2c = 9e-4f;
    float ssim_sum = 0.f;
    {
        int cc = tid & 31;
        int rb = (tid >> 5) << 2;
        float acc[4][5];
        #pragma unroll
        for (int u = 0; u < 4; ++u)
            #pragma unroll
            for (int q = 0; q < 5; ++q) acc[u][q] = 0.f;
        #pragma unroll
        for (int q = 0; q < 5; ++q) {
            const uint2* pp = (const uint2*)&hcT[q][cc][rb];
            uint2 d0 = pp[0], d1 = pp[1], d2 = pp[2], d3 = pp[3];
            unsigned int pr[7] = {d0.x, d0.y, d1.x, d1.y, d2.x, d2.y, d3.x};
            #pragma unroll
            for (int u = 0; u < 4; ++u)
                #pragma unroll
                for (int p = 0; p < 7; ++p)
                    acc[u][q] = dot2h(pr[p], gw[u][p], acc[u][q]);
        }
        #pragma unroll
        for (int u = 0; u < 4; ++u) {
            int gr = row0 + rb + u;
            if (gr < H) {   // gc always < W (W % 32 == 0)
                float mu1 = acc[u][0], mu2 = acc[u][1];
                float mu1s = mu1 * mu1, mu2s = mu2 * mu2, mu12 = mu1 * mu2;
                float s1  = acc[u][2] - mu1s;
                float s2  = acc[u][3] - mu2s;
                float s12 = acc[u][4] - mu12;
                float num = (2.f * mu12 + C1c) * (2.f * s12 + C2c);
                float den = (mu1s + mu2s + C1c) * (s1 + s2 + C2c);
                ssim_sum += num * __builtin_amdgcn_rcpf(den);
            }
        }
    }

    // ---- Block reduction, then hashed double atomics
    #pragma unroll
    for (int off = 32; off > 0; off >>= 1) {
        ssim_sum += __shfl_down(ssim_sum, off);
        l1_sum   += __shfl_down(l1_sum, off);
    }
    int wave = tid >> 6;
    if ((tid & 63) == 0) { red[wave] = ssim_sum; red[4 + wave] = l1_sum; }
    __syncthreads();
    if (tid == 0) {
        float s = red[0] + red[1] + red[2] + red[3];
        float l = red[4] + red[5] + red[6] + red[7];
        double* slot = accum + (size_t)(orig & (NSLOT - 1)) * 2;
        atomicAdd(&slot[0], (double)l);
        atomicAdd(&slot[1], (double)s);
    }
}

__global__ __launch_bounds__(NSLOT) void photo_final(
    const double* __restrict__ accum, float* __restrict__ out, double invN)
{
    __shared__ double sl[8], ss[8];
    int tid = threadIdx.x;
    double l = accum[tid * 2 + 0];
    double s = accum[tid * 2 + 1];
    #pragma unroll
    for (int off = 32; off > 0; off >>= 1) {
        l += __shfl_down(l, off);
        s += __shfl_down(s, off);
    }
    if ((tid & 63) == 0) { sl[tid >> 6] = l; ss[tid >> 6] = s; }
    __syncthreads();
    if (tid == 0) {
        double L = 0.0, S = 0.0;
        #pragma unroll
        for (int i = 0; i < NSLOT / 64; ++i) { L += sl[i]; S += ss[i]; }
        double l1    = L * invN;
        double ssim  = S * invN;
        double dssim = (1.0 - ssim) * 0.5;
        out[0] = (float)(0.8 * l1 + 0.2 * dssim);
        out[1] = (float)l1;
        out[2] = (float)dssim;
    }
}

extern "C" void kernel_launch(void* const* d_in, const int* in_sizes, int n_in,
                              void* d_out, int out_size, void* d_ws, size_t ws_size,
                              hipStream_t stream)
{
    const int H = 1080, W = 1920, C = 3;
    const float* x = (const float*)d_in[0];
    const float* y = (const float*)d_in[1];
    int B = in_sizes[0] / (H * W * C);

    double* accum = (double*)d_ws;
    hipMemsetAsync(d_ws, 0, NSLOT * 2 * sizeof(double), stream);

    dim3 grid((W / TW) * C, (H + TH - 1) / TH, B);
    int nwg = grid.x * grid.y * grid.z;
    photo_main<<<grid, dim3(256), 0, stream>>>(x, y, accum, B, H, W, C, nwg);

    double invN = 1.0 / ((double)B * H * W * C);
    photo_final<<<1, NSLOT, 0, stream>>>(accum, (float*)d_out, invN);
}

// Round 5
// 129.473 us; speedup vs baseline: 4.9661x; 1.3031x over previous
//
#include <hip/hip_runtime.h>
#include <hip/hip_fp16.h>

// PhotometricLoss: total = 0.8*L1 + 0.2*DSSIM; fused separable 11x11 Gaussian
// SSIM, SAME zero padding. Inputs BHWC fp32 (B=4,H=1080,W=1920,C=3).
// R5 (= R4 + compile fix): 4 moment planes {x, y, x2+y2, xy}, packed fp16
// column-pair dot2 h-pass, compile-time Gaussian weight tables, LDS 26.1KB.

typedef _Float16 h2_t __attribute__((ext_vector_type(2)));

#define TW 32
#define TH 32
#define IH 42         // tile rows incl halo
#define NPAIR 21      // column pairs (42 cols)
#define SPW 22        // sP row stride in uints (88B rows, b64-aligned)
#define HTR 44        // hcT row stride in halves (88B rows, b64-aligned)
#define NSLOT 512

#define HH 1080
#define WW 1920
#define GX 180        // (WW/TW)*3 channels
#define GY 34         // ceil(HH/TH)

// Gaussian(sigma=1.5, 11 taps), normalized; matches fp32 reference within ~2e-7
static constexpr float G[11] = {
    0.00102838f, 0.00759876f, 0.03600077f, 0.10936069f, 0.21300554f,
    0.26601174f, 0.21300554f, 0.10936069f, 0.03600077f, 0.00759876f,
    0.00102838f};

#define WV(m) (((m) >= 0 && (m) <= 10) ? G[((m) < 0) ? 0 : (((m) > 10) ? 10 : (m))] : 0.0f)

__device__ __forceinline__ unsigned short f2hbits(float x) {
    return __half_as_ushort(__float2half(x));
}
__device__ __forceinline__ unsigned int pkrtz(float a, float b) {
    return __builtin_bit_cast(unsigned int, __builtin_amdgcn_cvt_pkrtz(a, b));
}
__device__ __forceinline__ float dot2h(unsigned int a, unsigned int b, float c) {
#if __has_builtin(__builtin_amdgcn_fdot2)
    return __builtin_amdgcn_fdot2(__builtin_bit_cast(h2_t, a),
                                  __builtin_bit_cast(h2_t, b), c, false);
#else
    h2_t ah = __builtin_bit_cast(h2_t, a), bh = __builtin_bit_cast(h2_t, b);
    return c + (float)ah[0] * (float)bh[0] + (float)ah[1] * (float)bh[1];
#endif
}

__global__ __launch_bounds__(256, 6) void photo_main(
    const float* __restrict__ xin, const float* __restrict__ yin,
    double* __restrict__ accum, int B, int nwg)
{
    __shared__ unsigned int   sP[4][IH][SPW];    // packed col-pair fp16: x,y,x2+y2,xy
    __shared__ unsigned short hcT[4][TW][HTR];   // h-convolved, transposed
    __shared__ float red[8];

    // ---- bijective XCD swizzle (nwg % 8 == 0), channel fastest in x
    int orig = blockIdx.x + GX * (blockIdx.y + GY * blockIdx.z);
    int nid = ((nwg & 7) == 0) ? ((orig & 7) * (nwg >> 3) + (orig >> 3)) : orig;
    int bx   = nid % GX;           // constant divisor -> magic mul
    int rest = nid / GX;
    int by   = rest % GY;
    int b    = rest / GY;
    int c    = bx % 3;
    int tx   = bx / 3;
    const int row0 = by * TH, col0 = tx * TW;
    const int tid  = threadIdx.x;
    const int imgbase = b * (HH * WW * 3) + c;

    // ---- Phase 1a: stage 4 packed moment planes over the 42x42 halo tile;
    // fold L1 over the central 32x32. One item = one column PAIR.
    float l1_sum = 0.f;
    #pragma unroll 1
    for (int i = tid; i < IH * NPAIR; i += 256) {   // 882 items
        int r  = i / NPAIR;
        int pc = i - r * NPAIR;
        int gr  = row0 - 5 + r;
        int gc0 = col0 - 5 + 2 * pc;
        bool rin = (unsigned)gr < (unsigned)HH;
        bool c0  = rin && ((unsigned)gc0       < (unsigned)WW);
        bool c1  = rin && ((unsigned)(gc0 + 1) < (unsigned)WW);
        int base = imgbase + (gr * WW + gc0) * 3;
        float x0 = 0.f, x1 = 0.f, y0 = 0.f, y1 = 0.f;
        if (c0) { x0 = xin[base];     y0 = yin[base]; }
        if (c1) { x1 = xin[base + 3]; y1 = yin[base + 3]; }
        sP[0][r][pc] = pkrtz(x0, x1);
        sP[1][r][pc] = pkrtz(y0, y1);
        sP[2][r][pc] = pkrtz(x0 * x0 + y0 * y0, x1 * x1 + y1 * y1);
        sP[3][r][pc] = pkrtz(x0 * y0, x1 * y1);
        if (r >= 5 && r < 5 + TH) {
            if (c0 && pc >= 3 && pc <= 18) l1_sum += fabsf(x0 - y0);
            if (c1 && pc >= 2 && pc <= 17) l1_sum += fabsf(x1 - y1);
        }
    }
    __syncthreads();

    // ---- Phase 1b: horizontal 11-tap conv via packed dot2; item = (row, 4 cols)
    #pragma unroll 1
    for (int t = tid; t < IH * 8; t += 256) {       // 336 items
        int r  = t >> 3;
        int cb = (t & 7) << 2;
        int p0 = cb >> 1;                            // even
        #pragma unroll
        for (int q = 0; q < 4; ++q) {
            uint2 d0 = *(const uint2*)&sP[q][r][p0];
            uint2 d1 = *(const uint2*)&sP[q][r][p0 + 2];
            uint2 d2 = *(const uint2*)&sP[q][r][p0 + 4];
            unsigned e = sP[q][r][p0 + 6];
            unsigned pr[7] = {d0.x, d0.y, d1.x, d1.y, d2.x, d2.y, e};
            float a[4] = {0.f, 0.f, 0.f, 0.f};
            #pragma unroll
            for (int u = 0; u < 4; ++u) {
                #pragma unroll
                for (int p = 0; p < 7; ++p) {
                    const float w0 = WV(2 * p - u), w1 = WV(2 * p + 1 - u);
                    if (w0 != 0.f || w1 != 0.f) {
                        const unsigned gwc = (unsigned)f2hbits(w0) |
                                             ((unsigned)f2hbits(w1) << 16);
                        a[u] = dot2h(pr[p], gwc, a[u]);
                    }
                }
            }
            #pragma unroll
            for (int u = 0; u < 4; ++u)
                hcT[q][cb + u][r] = f2hbits(a[u]);
        }
    }
    __syncthreads();

    // ---- Phase 2: vertical conv via dot2 on contiguous row pairs + SSIM.
    const float C1c = 1e-4f, C2c = 9e-4f;
    float ssim_sum = 0.f;
    {
        int cc = tid & 31;
        int rb = (tid >> 5) << 2;
        float acc[4][4];                 // [u][q]
        #pragma unroll
        for (int u = 0; u < 4; ++u)
            #pragma unroll
            for (int q = 0; q < 4; ++q) acc[u][q] = 0.f;
        #pragma unroll
        for (int q = 0; q < 4; ++q) {
            uint2 d0 = *(const uint2*)&hcT[q][cc][rb];
            uint2 d1 = *(const uint2*)&hcT[q][cc][rb + 4];
            uint2 d2 = *(const uint2*)&hcT[q][cc][rb + 8];
            unsigned e = *(const unsigned*)&hcT[q][cc][rb + 12];
            unsigned pr[7] = {d0.x, d0.y, d1.x, d1.y, d2.x, d2.y, e};
            #pragma unroll
            for (int u = 0; u < 4; ++u) {
                #pragma unroll
                for (int p = 0; p < 7; ++p) {
                    const float w0 = WV(2 * p - u), w1 = WV(2 * p + 1 - u);
                    if (w0 != 0.f || w1 != 0.f) {
                        const unsigned gwc = (unsigned)f2hbits(w0) |
                                             ((unsigned)f2hbits(w1) << 16);
                        acc[u][q] = dot2h(pr[p], gwc, acc[u][q]);
                    }
                }
            }
        }
        #pragma unroll
        for (int u = 0; u < 4; ++u) {
            int gr = row0 + rb + u;
            if (gr < HH) {               // cols always in range (WW % 32 == 0)
                float mu1 = acc[u][0], mu2 = acc[u][1];
                float mu1s = mu1 * mu1, mu2s = mu2 * mu2, mu12 = mu1 * mu2;
                float ssum = acc[u][2] - mu1s - mu2s;   // sigma1^2 + sigma2^2
                float s12  = acc[u][3] - mu12;
                float num = (2.f * mu12 + C1c) * (2.f * s12 + C2c);
                float den = (mu1s + mu2s + C1c) * (ssum + C2c);
                ssim_sum += num * __builtin_amdgcn_rcpf(den);
            }
        }
    }

    // ---- Block reduction, then hashed double atomics
    #pragma unroll
    for (int off = 32; off > 0; off >>= 1) {
        ssim_sum += __shfl_down(ssim_sum, off);
        l1_sum   += __shfl_down(l1_sum, off);
    }
    int wave = tid >> 6;
    if ((tid & 63) == 0) { red[wave] = ssim_sum; red[4 + wave] = l1_sum; }
    __syncthreads();
    if (tid == 0) {
        float s = red[0] + red[1] + red[2] + red[3];
        float l = red[4] + red[5] + red[6] + red[7];
        double* slot = accum + (size_t)(orig & (NSLOT - 1)) * 2;
        atomicAdd(&slot[0], (double)l);
        atomicAdd(&slot[1], (double)s);
    }
}

__global__ __launch_bounds__(NSLOT) void photo_final(
    const double* __restrict__ accum, float* __restrict__ out, double invN)
{
    __shared__ double sl[8], ss[8];
    int tid = threadIdx.x;
    double l = accum[tid * 2 + 0];
    double s = accum[tid * 2 + 1];
    #pragma unroll
    for (int off = 32; off > 0; off >>= 1) {
        l += __shfl_down(l, off);
        s += __shfl_down(s, off);
    }
    if ((tid & 63) == 0) { sl[tid >> 6] = l; ss[tid >> 6] = s; }
    __syncthreads();
    if (tid == 0) {
        double L = 0.0, S = 0.0;
        #pragma unroll
        for (int i = 0; i < NSLOT / 64; ++i) { L += sl[i]; S += ss[i]; }
        double l1    = L * invN;
        double ssim  = S * invN;
        double dssim = (1.0 - ssim) * 0.5;
        out[0] = (float)(0.8 * l1 + 0.2 * dssim);
        out[1] = (float)l1;
        out[2] = (float)dssim;
    }
}

extern "C" void kernel_launch(void* const* d_in, const int* in_sizes, int n_in,
                              void* d_out, int out_size, void* d_ws, size_t ws_size,
                              hipStream_t stream)
{
    const int H = 1080, W = 1920, C = 3;
    const float* x = (const float*)d_in[0];
    const float* y = (const float*)d_in[1];
    int B = in_sizes[0] / (H * W * C);

    double* accum = (double*)d_ws;
    hipMemsetAsync(d_ws, 0, NSLOT * 2 * sizeof(double), stream);

    dim3 grid(GX, GY, B);
    int nwg = GX * GY * B;
    photo_main<<<grid, dim3(256), 0, stream>>>(x, y, accum, B, nwg);

    double invN = 1.0 / ((double)B * H * W * C);
    photo_final<<<1, NSLOT, 0, stream>>>(accum, (float*)d_out, invN);
}

// Round 6
// 114.413 us; speedup vs baseline: 5.6198x; 1.1316x over previous
//
#include <hip/hip_runtime.h>
#include <hip/hip_fp16.h>

// PhotometricLoss: total = 0.8*L1 + 0.2*DSSIM; fused separable 11x11 Gaussian
// SSIM, SAME zero padding. Inputs BHWC fp32 (B=4,H=1080,W=1920,C=3).
// R6: LDS aliasing (h-conv result overwrites its own source plane) ->
// 14.8KB -> 8 blocks/CU (100% occ cap); interior-block fast path staging
// (dwordx4, no bounds); static two-item phase-1b (no scratch).

typedef _Float16 h2_t __attribute__((ext_vector_type(2)));

#define TW 32
#define TH 32
#define IH 42         // tile rows incl halo
#define NPAIR 21      // column pairs (42 cols)
#define SPW 22        // sP row stride in uints (88B rows, b64-aligned)
#define PLANE 924     // IH*SPW uints per plane
#define HTR 44        // h-conv region row stride in halves (88B, b64-aligned)
#define NSLOT 512

#define HH 1080
#define WW 1920
#define GX 180        // (WW/TW)*3 channels
#define GY 34         // ceil(HH/TH)

// Gaussian(sigma=1.5, 11 taps), normalized; matches fp32 reference within ~2e-7
static constexpr float G[11] = {
    0.00102838f, 0.00759876f, 0.03600077f, 0.10936069f, 0.21300554f,
    0.26601174f, 0.21300554f, 0.10936069f, 0.03600077f, 0.00759876f,
    0.00102838f};

#define WV(m) (((m) >= 0 && (m) <= 10) ? G[((m) < 0) ? 0 : (((m) > 10) ? 10 : (m))] : 0.0f)

struct f4u { float x, y, z, w; } __attribute__((packed, aligned(4)));

__device__ __forceinline__ unsigned short f2hbits(float x) {
    return __half_as_ushort(__float2half(x));
}
__device__ __forceinline__ unsigned int pkrtz(float a, float b) {
    return __builtin_bit_cast(unsigned int, __builtin_amdgcn_cvt_pkrtz(a, b));
}
__device__ __forceinline__ float dot2h(unsigned int a, unsigned int b, float c) {
#if __has_builtin(__builtin_amdgcn_fdot2)
    return __builtin_amdgcn_fdot2(__builtin_bit_cast(h2_t, a),
                                  __builtin_bit_cast(h2_t, b), c, false);
#else
    h2_t ah = __builtin_bit_cast(h2_t, a), bh = __builtin_bit_cast(h2_t, b);
    return c + (float)ah[0] * (float)bh[0] + (float)ah[1] * (float)bh[1];
#endif
}

// horizontal 11-tap conv of one plane, one item = (row, 4 output cols)
__device__ __forceinline__ void h_item(const unsigned* __restrict__ spq,
                                       int t, float a[4]) {
    int r  = t >> 3;
    int p0 = (t & 7) << 1;                 // starting column pair (even)
    const unsigned* sp = spq + r * SPW + p0;
    uint2 d0 = *(const uint2*)&sp[0];
    uint2 d1 = *(const uint2*)&sp[2];
    uint2 d2 = *(const uint2*)&sp[4];
    unsigned e = sp[6];
    unsigned pr[7] = {d0.x, d0.y, d1.x, d1.y, d2.x, d2.y, e};
    a[0] = a[1] = a[2] = a[3] = 0.f;
    #pragma unroll
    for (int u = 0; u < 4; ++u) {
        #pragma unroll
        for (int p = 0; p < 7; ++p) {
            const float w0 = WV(2 * p - u), w1 = WV(2 * p + 1 - u);
            if (w0 != 0.f || w1 != 0.f) {
                const unsigned gwc = (unsigned)f2hbits(w0) |
                                     ((unsigned)f2hbits(w1) << 16);
                a[u] = dot2h(pr[p], gwc, a[u]);
            }
        }
    }
}
__device__ __forceinline__ void h_write(unsigned short* __restrict__ hq,
                                        int t, const float a[4]) {
    int r  = t >> 3;
    int cb = (t & 7) << 2;
    #pragma unroll
    for (int u = 0; u < 4; ++u) hq[(cb + u) * HTR + r] = f2hbits(a[u]);
}

__global__ __launch_bounds__(256, 8) void photo_main(
    const float* __restrict__ xin, const float* __restrict__ yin,
    double* __restrict__ accum, int B, int nwg)
{
    __shared__ unsigned int sPbuf[4 * PLANE];   // 14784 B; planes aliased in-place
    __shared__ float red[8];

    // ---- bijective XCD swizzle (nwg % 8 == 0), channel fastest in x
    int orig = blockIdx.x + GX * (blockIdx.y + GY * blockIdx.z);
    int nid = ((nwg & 7) == 0) ? ((orig & 7) * (nwg >> 3) + (orig >> 3)) : orig;
    int bx   = nid % GX;
    int rest = nid / GX;
    int by   = rest % GY;
    int b    = rest / GY;
    int c    = bx % 3;
    int tx   = bx / 3;
    const int row0 = by * TH, col0 = tx * TW;
    const int tid  = threadIdx.x;
    const int imgbase = b * (HH * WW * 3) + c;

    // ---- Phase 1a: stage 4 packed fp16 moment planes {x,y,x2+y2,xy} over the
    // 42x42 halo tile; fold L1 over the central 32x32.
    float l1_sum = 0.f;
    const bool interior = (tx >= 1) && (tx <= 58) && (by >= 1) && (by <= 32);
    if (interior) {
        for (int i = tid; i < IH * NPAIR; i += 256) {
            int r  = i / NPAIR;
            int pc = i - r * NPAIR;
            int gr  = row0 - 5 + r;
            int gc0 = col0 - 5 + 2 * pc;
            int base = imgbase + (gr * WW + gc0) * 3;
            f4u vx = *(const f4u*)&xin[base];     // x0 = .x, x1 = .w (stride-3)
            f4u vy = *(const f4u*)&yin[base];
            float x0 = vx.x, x1 = vx.w, y0 = vy.x, y1 = vy.w;
            sPbuf[0 * PLANE + r * SPW + pc] = pkrtz(x0, x1);
            sPbuf[1 * PLANE + r * SPW + pc] = pkrtz(y0, y1);
            sPbuf[2 * PLANE + r * SPW + pc] =
                pkrtz(x0 * x0 + y0 * y0, x1 * x1 + y1 * y1);
            sPbuf[3 * PLANE + r * SPW + pc] = pkrtz(x0 * y0, x1 * y1);
            if (r >= 5 && r < 5 + TH) {
                if (pc >= 3 && pc <= 18) l1_sum += fabsf(x0 - y0);
                if (pc >= 2 && pc <= 17) l1_sum += fabsf(x1 - y1);
            }
        }
    } else {
        #pragma unroll 1
        for (int i = tid; i < IH * NPAIR; i += 256) {
            int r  = i / NPAIR;
            int pc = i - r * NPAIR;
            int gr  = row0 - 5 + r;
            int gc0 = col0 - 5 + 2 * pc;
            bool rin = (unsigned)gr < (unsigned)HH;
            bool c0  = rin && ((unsigned)gc0       < (unsigned)WW);
            bool c1  = rin && ((unsigned)(gc0 + 1) < (unsigned)WW);
            int base = imgbase + (gr * WW + gc0) * 3;
            float x0 = 0.f, x1 = 0.f, y0 = 0.f, y1 = 0.f;
            if (c0) { x0 = xin[base];     y0 = yin[base]; }
            if (c1) { x1 = xin[base + 3]; y1 = yin[base + 3]; }
            sPbuf[0 * PLANE + r * SPW + pc] = pkrtz(x0, x1);
            sPbuf[1 * PLANE + r * SPW + pc] = pkrtz(y0, y1);
            sPbuf[2 * PLANE + r * SPW + pc] =
                pkrtz(x0 * x0 + y0 * y0, x1 * x1 + y1 * y1);
            sPbuf[3 * PLANE + r * SPW + pc] = pkrtz(x0 * y0, x1 * y1);
            if (r >= 5 && r < 5 + TH) {
                if (c0 && pc >= 3 && pc <= 18) l1_sum += fabsf(x0 - y0);
                if (c1 && pc >= 2 && pc <= 17) l1_sum += fabsf(x1 - y1);
            }
        }
    }
    __syncthreads();

    // ---- Phase 1b: per plane: h-conv to regs, barrier, write result OVER the
    // same plane's storage (transposed, fp16, 32 rows x HTR halves), barrier.
    // 336 items, 256 threads: item tid always, item tid+256 iff tid < 80.
    const bool has2 = tid < (IH * 8 - 256);
    #pragma unroll 1
    for (int q = 0; q < 4; ++q) {
        const unsigned* spq = &sPbuf[q * PLANE];
        float a0[4], a1[4];
        h_item(spq, tid, a0);
        if (has2) h_item(spq, tid + 256, a1);
        __syncthreads();
        unsigned short* hq = (unsigned short*)&sPbuf[q * PLANE];
        h_write(hq, tid, a0);
        if (has2) h_write(hq, tid + 256, a1);
        __syncthreads();
    }

    // ---- Phase 2: vertical conv via dot2 on contiguous row pairs + SSIM.
    const float C1c = 1e-4f, C2c = 9e-4f;
    float ssim_sum = 0.f;
    {
        int cc = tid & 31;
        int rb = (tid >> 5) << 2;
        float acc[4][4];                 // [u][q]
        #pragma unroll
        for (int u = 0; u < 4; ++u)
            #pragma unroll
            for (int q = 0; q < 4; ++q) acc[u][q] = 0.f;
        #pragma unroll
        for (int q = 0; q < 4; ++q) {
            const unsigned short* hq = (const unsigned short*)&sPbuf[q * PLANE];
            const unsigned short* hp = &hq[cc * HTR + rb];
            uint2 d0 = *(const uint2*)&hp[0];
            uint2 d1 = *(const uint2*)&hp[4];
            uint2 d2 = *(const uint2*)&hp[8];
            unsigned e = *(const unsigned*)&hp[12];
            unsigned pr[7] = {d0.x, d0.y, d1.x, d1.y, d2.x, d2.y, e};
            #pragma unroll
            for (int u = 0; u < 4; ++u) {
                #pragma unroll
                for (int p = 0; p < 7; ++p) {
                    const float w0 = WV(2 * p - u), w1 = WV(2 * p + 1 - u);
                    if (w0 != 0.f || w1 != 0.f) {
                        const unsigned gwc = (unsigned)f2hbits(w0) |
                                             ((unsigned)f2hbits(w1) << 16);
                        acc[u][q] = dot2h(pr[p], gwc, acc[u][q]);
                    }
                }
            }
        }
        #pragma unroll
        for (int u = 0; u < 4; ++u) {
            int gr = row0 + rb + u;
            if (gr < HH) {               // cols always in range (WW % 32 == 0)
                float mu1 = acc[u][0], mu2 = acc[u][1];
                float mu1s = mu1 * mu1, mu2s = mu2 * mu2, mu12 = mu1 * mu2;
                float ssum = acc[u][2] - mu1s - mu2s;   // sigma1^2 + sigma2^2
                float s12  = acc[u][3] - mu12;
                float num = (2.f * mu12 + C1c) * (2.f * s12 + C2c);
                float den = (mu1s + mu2s + C1c) * (ssum + C2c);
                ssim_sum += num * __builtin_amdgcn_rcpf(den);
            }
        }
    }

    // ---- Block reduction, then hashed double atomics
    #pragma unroll
    for (int off = 32; off > 0; off >>= 1) {
        ssim_sum += __shfl_down(ssim_sum, off);
        l1_sum   += __shfl_down(l1_sum, off);
    }
    int wave = tid >> 6;
    if ((tid & 63) == 0) { red[wave] = ssim_sum; red[4 + wave] = l1_sum; }
    __syncthreads();
    if (tid == 0) {
        float s = red[0] + red[1] + red[2] + red[3];
        float l = red[4] + red[5] + red[6] + red[7];
        double* slot = accum + (size_t)(orig & (NSLOT - 1)) * 2;
        atomicAdd(&slot[0], (double)l);
        atomicAdd(&slot[1], (double)s);
    }
}

__global__ __launch_bounds__(NSLOT) void photo_final(
    const double* __restrict__ accum, float* __restrict__ out, double invN)
{
    __shared__ double sl[8], ss[8];
    int tid = threadIdx.x;
    double l = accum[tid * 2 + 0];
    double s = accum[tid * 2 + 1];
    #pragma unroll
    for (int off = 32; off > 0; off >>= 1) {
        l += __shfl_down(l, off);
        s += __shfl_down(s, off);
    }
    if ((tid & 63) == 0) { sl[tid >> 6] = l; ss[tid >> 6] = s; }
    __syncthreads();
    if (tid == 0) {
        double L = 0.0, S = 0.0;
        #pragma unroll
        for (int i = 0; i < NSLOT / 64; ++i) { L += sl[i]; S += ss[i]; }
        double l1    = L * invN;
        double ssim  = S * invN;
        double dssim = (1.0 - ssim) * 0.5;
        out[0] = (float)(0.8 * l1 + 0.2 * dssim);
        out[1] = (float)l1;
        out[2] = (float)dssim;
    }
}

extern "C" void kernel_launch(void* const* d_in, const int* in_sizes, int n_in,
                              void* d_out, int out_size, void* d_ws, size_t ws_size,
                              hipStream_t stream)
{
    const int H = 1080, W = 1920, C = 3;
    const float* x = (const float*)d_in[0];
    const float* y = (const float*)d_in[1];
    int B = in_sizes[0] / (H * W * C);

    double* accum = (double*)d_ws;
    hipMemsetAsync(d_ws, 0, NSLOT * 2 * sizeof(double), stream);

    dim3 grid(GX, GY, B);
    int nwg = GX * GY * B;
    photo_main<<<grid, dim3(256), 0, stream>>>(x, y, accum, B, nwg);

    double invN = 1.0 / ((double)B * H * W * C);
    photo_final<<<1, NSLOT, 0, stream>>>(accum, (float*)d_out, invN);
}